// Round 1
// baseline (204.255 us; speedup 1.0000x reference)
//
#include <hip/hip_runtime.h>
#include <hip/hip_bf16.h>
#include <stdint.h>

#define MDIM 16384   // B*S = 4*4096
#define NDIM 2048    // MAX_OUT
#define KDIM 2048    // MAX_IN

typedef __attribute__((ext_vector_type(4))) float f32x4;
typedef __attribute__((ext_vector_type(8))) short s16x8;

__device__ __forceinline__ void gload_lds16(const __hip_bfloat16* g, __hip_bfloat16* l) {
    __builtin_amdgcn_global_load_lds(
        (const __attribute__((address_space(1))) void*)g,
        (__attribute__((address_space(3))) void*)l,
        16, 0, 0);
}

// ---------------- prep kernels ----------------

// x_mix[e] = A0 * fq(x, a_s0, 4) + A1 * fq(x, a_s1, 8), stored bf16.
__global__ __launch_bounds__(256) void prep_x(
    const float* __restrict__ x, const float* __restrict__ weights,
    const float* __restrict__ a_scales, __hip_bfloat16* __restrict__ xq)
{
    float A0 = 0.f, A1 = 0.f;
    #pragma unroll
    for (int k = 0; k < 16; ++k) {
        float w = weights[k];
        if (((k >> 1) & 1) == 0) A0 += w; else A1 += w;
    }
    const float s0 = a_scales[0], s1 = a_scales[1];
    const float r0 = 1.f / s0, r1 = 1.f / s1;

    size_t idx = ((size_t)blockIdx.x * 256 + threadIdx.x) * 8;
    const f32x4* xv = (const f32x4*)(x + idx);
    f32x4 v0 = xv[0], v1 = xv[1];
    float vals[8] = {v0.x, v0.y, v0.z, v0.w, v1.x, v1.y, v1.z, v1.w};

    union { s16x8 v; __hip_bfloat16 h[8]; } u;
    #pragma unroll
    for (int j = 0; j < 8; ++j) {
        float q0 = rintf(fminf(fmaxf(vals[j] * r0, -8.f),   7.f)) * s0;
        float q1 = rintf(fminf(fmaxf(vals[j] * r1, -128.f), 127.f)) * s1;
        u.h[j] = __float2bfloat16(A0 * q0 + A1 * q1);
    }
    *(s16x8*)(xq + idx) = u.v;
}

// w_mix[o,c] = coef0(o,c)*fq(W,ws0,4) + coef1(o,c)*fq(W,ws1,8), stored bf16.
__global__ __launch_bounds__(256) void prep_w(
    const float* __restrict__ W, const float* __restrict__ weights,
    const float* __restrict__ w_scales, __hip_bfloat16* __restrict__ wq)
{
    float c00 = weights[0] + weights[2]  + weights[4]  + weights[6];
    float c01 = weights[1] + weights[3]  + weights[5]  + weights[7];
    float c10 = weights[8] + weights[10] + weights[12] + weights[14];
    float c11 = weights[9] + weights[11] + weights[13] + weights[15];

    const float s0 = w_scales[0], s1 = w_scales[1];
    const float r0 = 1.f / s0, r1 = 1.f / s1;

    size_t idx = ((size_t)blockIdx.x * 256 + threadIdx.x) * 8;
    const int o = (int)(idx >> 11);
    const int c = (int)(idx & 2047);
    const bool inner = (o < 1024) && (c < 1024);  // whole 8-elem chunk same region
    const float k0 = inner ? (c00 + c10) : c10;
    const float k1 = inner ? (c01 + c11) : c11;

    const f32x4* wv = (const f32x4*)(W + idx);
    f32x4 v0 = wv[0], v1 = wv[1];
    float vals[8] = {v0.x, v0.y, v0.z, v0.w, v1.x, v1.y, v1.z, v1.w};

    union { s16x8 v; __hip_bfloat16 h[8]; } u;
    #pragma unroll
    for (int j = 0; j < 8; ++j) {
        float q0 = rintf(fminf(fmaxf(vals[j] * r0, -8.f),   7.f)) * s0;
        float q1 = rintf(fminf(fmaxf(vals[j] * r1, -128.f), 127.f)) * s1;
        u.h[j] = __float2bfloat16(k0 * q0 + k1 * q1);
    }
    *(s16x8*)(wq + idx) = u.v;
}

// b_mix[o] = b[o] * (o<1024 ? sum(all w) : sum(w[8:16]))
__global__ __launch_bounds__(256) void prep_b(
    const float* __restrict__ b, const float* __restrict__ weights,
    float* __restrict__ bm)
{
    int o = blockIdx.x * 256 + threadIdx.x;
    if (o >= NDIM) return;
    float S1 = 0.f, S0 = 0.f;
    #pragma unroll
    for (int k = 0; k < 8; ++k)  S0 += weights[k];
    #pragma unroll
    for (int k = 8; k < 16; ++k) S1 += weights[k];
    bm[o] = b[o] * ((o < 1024) ? (S0 + S1) : S1);
}

// ---------------- GEMM: C[m,o] = sum_k A[m,k]*B[o,k] + bias[o] ----------------
// m97 structure: 128x128 tile, BK=32, 4 waves (2x2), 4x4 16x16x32 frags/wave,
// double-buffered LDS staged via global_load_lds width=16.

__global__ __launch_bounds__(256) void gemm_bt(
    const __hip_bfloat16* __restrict__ A,
    const __hip_bfloat16* __restrict__ B,
    const float* __restrict__ bias,
    float* __restrict__ C)
{
    __shared__ __hip_bfloat16 lds[2][2][128 * 32];

    const int tid  = threadIdx.x;
    const int lane = tid & 63;
    const int wid  = tid >> 6;
    const int wm   = wid >> 1;   // wave row (0..1)
    const int wn   = wid & 1;    // wave col (0..1)
    const int brow = blockIdx.y * 128;
    const int bcol = blockIdx.x * 128;

    // staging source: thread t covers row t/4 (+64 for 2nd issue), 8 bf16 at col (t%4)*8
    const __hip_bfloat16* Ag = A + (size_t)(brow + (tid >> 2)) * KDIM + (tid & 3) * 8;
    const __hip_bfloat16* Bg = B + (size_t)(bcol + (tid >> 2)) * KDIM + (tid & 3) * 8;
    const size_t half = (size_t)64 * KDIM;

    f32x4 acc[4][4];
    #pragma unroll
    for (int m = 0; m < 4; ++m)
        #pragma unroll
        for (int n = 0; n < 4; ++n)
            acc[m][n] = (f32x4){0.f, 0.f, 0.f, 0.f};

    // prologue: stage tile 0 into buf 0
    gload_lds16(Ag,        &lds[0][0][tid * 8]);
    gload_lds16(Ag + half, &lds[0][0][2048 + tid * 8]);
    gload_lds16(Bg,        &lds[0][1][tid * 8]);
    gload_lds16(Bg + half, &lds[0][1][2048 + tid * 8]);
    __syncthreads();

    const int koff = (lane >> 4) * 8;       // k sub-block per lane group
    const int fr   = lane & 15;             // fragment row/col within 16

    int cur = 0;
    #pragma unroll 1
    for (int kt = 0; kt < KDIM / 32; ++kt) {
        if (kt + 1 < KDIM / 32) {
            const size_t go = (size_t)(kt + 1) * 32;
            const int nb = cur ^ 1;
            gload_lds16(Ag + go,        &lds[nb][0][tid * 8]);
            gload_lds16(Ag + go + half, &lds[nb][0][2048 + tid * 8]);
            gload_lds16(Bg + go,        &lds[nb][1][tid * 8]);
            gload_lds16(Bg + go + half, &lds[nb][1][2048 + tid * 8]);
        }
        s16x8 af[4], bf[4];
        #pragma unroll
        for (int m = 0; m < 4; ++m)
            af[m] = *(const s16x8*)&lds[cur][0][(wm * 64 + m * 16 + fr) * 32 + koff];
        #pragma unroll
        for (int n = 0; n < 4; ++n)
            bf[n] = *(const s16x8*)&lds[cur][1][(wn * 64 + n * 16 + fr) * 32 + koff];
        #pragma unroll
        for (int m = 0; m < 4; ++m)
            #pragma unroll
            for (int n = 0; n < 4; ++n)
                acc[m][n] = __builtin_amdgcn_mfma_f32_16x16x32_bf16(af[m], bf[n], acc[m][n], 0, 0, 0);
        __syncthreads();   // drains vmcnt (staging) + lgkmcnt (ds reads)
        cur ^= 1;
    }

    // epilogue: C/D layout col = lane&15, row = (lane>>4)*4 + j   [m89]
    const int ccol0 = bcol + wn * 64 + fr;
    const int crow0 = brow + wm * 64 + (lane >> 4) * 4;
    float bv[4];
    #pragma unroll
    for (int n = 0; n < 4; ++n) bv[n] = bias[ccol0 + n * 16];

    #pragma unroll
    for (int m = 0; m < 4; ++m) {
        #pragma unroll
        for (int j = 0; j < 4; ++j) {
            float* Crow = C + (size_t)(crow0 + m * 16 + j) * NDIM;
            #pragma unroll
            for (int n = 0; n < 4; ++n)
                Crow[ccol0 + n * 16] = acc[m][n][j] + bv[n];
        }
    }
}

// ---------------- launcher ----------------

extern "C" void kernel_launch(void* const* d_in, const int* in_sizes, int n_in,
                              void* d_out, int out_size, void* d_ws, size_t ws_size,
                              hipStream_t stream) {
    const float* x        = (const float*)d_in[0];  // [4,4096,2048]
    const float* weights  = (const float*)d_in[1];  // [16]
    const float* W        = (const float*)d_in[2];  // [2048,2048]
    const float* b        = (const float*)d_in[3];  // [2048]
    const float* a_scales = (const float*)d_in[4];  // [2]
    const float* w_scales = (const float*)d_in[5];  // [2]
    float* out = (float*)d_out;

    // workspace layout
    __hip_bfloat16* xq = (__hip_bfloat16*)d_ws;                            // 67108864 B
    __hip_bfloat16* wq = (__hip_bfloat16*)((char*)d_ws + 67108864);        //  8388608 B
    float*          bm = (float*)((char*)d_ws + 67108864 + 8388608);       //     8192 B

    prep_w<<<dim3((NDIM * KDIM) / (256 * 8)), dim3(256), 0, stream>>>(W, weights, w_scales, wq);
    prep_b<<<dim3(NDIM / 256), dim3(256), 0, stream>>>(b, weights, bm);
    prep_x<<<dim3(((size_t)MDIM * KDIM) / (256 * 8)), dim3(256), 0, stream>>>(x, weights, a_scales, xq);
    gemm_bt<<<dim3(NDIM / 128, MDIM / 128), dim3(256), 0, stream>>>(xq, wq, bm, out);
}

// Round 2
// 183.241 us; speedup vs baseline: 1.1147x; 1.1147x over previous
//
#include <hip/hip_runtime.h>
#include <hip/hip_bf16.h>
#include <stdint.h>

#define MDIM 16384   // B*S = 4*4096
#define NDIM 2048    // MAX_OUT
#define KDIM 2048    // MAX_IN

typedef __attribute__((ext_vector_type(4))) float f32x4;
typedef __attribute__((ext_vector_type(8))) short s16x8;

__device__ __forceinline__ void gload_lds16(const __hip_bfloat16* g, void* l) {
    __builtin_amdgcn_global_load_lds(
        (const __attribute__((address_space(1))) void*)g,
        (__attribute__((address_space(3))) void*)l,
        16, 0, 0);
}

// ---------------- prep kernels (unchanged, near-BW) ----------------

__global__ __launch_bounds__(256) void prep_x(
    const float* __restrict__ x, const float* __restrict__ weights,
    const float* __restrict__ a_scales, __hip_bfloat16* __restrict__ xq)
{
    float A0 = 0.f, A1 = 0.f;
    #pragma unroll
    for (int k = 0; k < 16; ++k) {
        float w = weights[k];
        if (((k >> 1) & 1) == 0) A0 += w; else A1 += w;
    }
    const float s0 = a_scales[0], s1 = a_scales[1];
    const float r0 = 1.f / s0, r1 = 1.f / s1;

    size_t idx = ((size_t)blockIdx.x * 256 + threadIdx.x) * 8;
    const f32x4* xv = (const f32x4*)(x + idx);
    f32x4 v0 = xv[0], v1 = xv[1];
    float vals[8] = {v0.x, v0.y, v0.z, v0.w, v1.x, v1.y, v1.z, v1.w};

    union { s16x8 v; __hip_bfloat16 h[8]; } u;
    #pragma unroll
    for (int j = 0; j < 8; ++j) {
        float q0 = rintf(fminf(fmaxf(vals[j] * r0, -8.f),   7.f)) * s0;
        float q1 = rintf(fminf(fmaxf(vals[j] * r1, -128.f), 127.f)) * s1;
        u.h[j] = __float2bfloat16(A0 * q0 + A1 * q1);
    }
    *(s16x8*)(xq + idx) = u.v;
}

__global__ __launch_bounds__(256) void prep_w(
    const float* __restrict__ W, const float* __restrict__ weights,
    const float* __restrict__ w_scales, __hip_bfloat16* __restrict__ wq)
{
    float c00 = weights[0] + weights[2]  + weights[4]  + weights[6];
    float c01 = weights[1] + weights[3]  + weights[5]  + weights[7];
    float c10 = weights[8] + weights[10] + weights[12] + weights[14];
    float c11 = weights[9] + weights[11] + weights[13] + weights[15];

    const float s0 = w_scales[0], s1 = w_scales[1];
    const float r0 = 1.f / s0, r1 = 1.f / s1;

    size_t idx = ((size_t)blockIdx.x * 256 + threadIdx.x) * 8;
    const int o = (int)(idx >> 11);
    const int c = (int)(idx & 2047);
    const bool inner = (o < 1024) && (c < 1024);
    const float k0 = inner ? (c00 + c10) : c10;
    const float k1 = inner ? (c01 + c11) : c11;

    const f32x4* wv = (const f32x4*)(W + idx);
    f32x4 v0 = wv[0], v1 = wv[1];
    float vals[8] = {v0.x, v0.y, v0.z, v0.w, v1.x, v1.y, v1.z, v1.w};

    union { s16x8 v; __hip_bfloat16 h[8]; } u;
    #pragma unroll
    for (int j = 0; j < 8; ++j) {
        float q0 = rintf(fminf(fmaxf(vals[j] * r0, -8.f),   7.f)) * s0;
        float q1 = rintf(fminf(fmaxf(vals[j] * r1, -128.f), 127.f)) * s1;
        u.h[j] = __float2bfloat16(k0 * q0 + k1 * q1);
    }
    *(s16x8*)(wq + idx) = u.v;
}

__global__ __launch_bounds__(256) void prep_b(
    const float* __restrict__ b, const float* __restrict__ weights,
    float* __restrict__ bm)
{
    int o = blockIdx.x * 256 + threadIdx.x;
    if (o >= NDIM) return;
    float S1 = 0.f, S0 = 0.f;
    #pragma unroll
    for (int k = 0; k < 8; ++k)  S0 += weights[k];
    #pragma unroll
    for (int k = 8; k < 16; ++k) S1 += weights[k];
    bm[o] = b[o] * ((o < 1024) ? (S0 + S1) : S1);
}

// ---------------- GEMM: 256x256 tile, BK=32, 8 waves, 2-phase/K-tile,
// triple-buffered LDS, counted vmcnt(4), swizzled LDS (T2), setprio (T5) ----

#define BM 256
#define BN 256
#define BK 32
#define NKT (KDIM / BK)          // 64
#define ABYTES (BM * BK * 2)     // 16384 bytes per A-tile
#define BUFBYTES (2 * ABYTES)    // 32768 bytes per K-tile buffer (A+B)

#define MFMA(a, b, c) __builtin_amdgcn_mfma_f32_16x16x32_bf16((a), (b), (c), 0, 0, 0)

__global__ __launch_bounds__(512, 2) void gemm256(
    const __hip_bfloat16* __restrict__ A,
    const __hip_bfloat16* __restrict__ B,
    const float* __restrict__ bias,
    float* __restrict__ C)
{
    __shared__ char lds[3 * BUFBYTES];   // 96 KiB

    const int tid  = threadIdx.x;
    const int lane = tid & 63;
    const int wid  = tid >> 6;    // 0..7
    const int wm   = wid >> 2;    // 0..1  (M half)
    const int wn   = wid & 3;     // 0..3  (N quarter)
    const int brow = blockIdx.y * BM;
    const int bcol = blockIdx.x * BN;

    // ---- staging constants: linear LDS dest, pre-swizzled global source ----
    // chunk i (0..1023): row = i>>2, slot = i&3; content chunk c = slot ^ ((row>>1)&3)
    const int i0 = tid, i1 = tid + 512;
    const int r0 = i0 >> 2, c0 = (i0 & 3) ^ ((i0 >> 3) & 3);
    const int r1 = i1 >> 2, c1 = (i1 & 3) ^ ((i1 >> 3) & 3);
    const __hip_bfloat16* As0 = A + (size_t)(brow + r0) * KDIM + c0 * 8;
    const __hip_bfloat16* As1 = A + (size_t)(brow + r1) * KDIM + c1 * 8;
    const __hip_bfloat16* Bs0 = B + (size_t)(bcol + r0) * KDIM + c0 * 8;
    const __hip_bfloat16* Bs1 = B + (size_t)(bcol + r1) * KDIM + c1 * 8;
    const int ld0 = i0 * 16, ld1 = i1 * 16;

    // ---- compute-read constants (swizzled; XOR is lane-constant) ----
    const int fr  = lane & 15;
    const int l16 = lane >> 4;                       // k-chunk 0..3
    const int xr  = (l16 ^ ((fr >> 1) & 3)) * 16;    // swizzled 16B slot
    const int aoff = (wm * 128 + fr) * 64 + xr;      // + m*1024
    const int boff = (wn * 64  + fr) * 64 + xr;      // + nh*2048 + nn*1024

    f32x4 acc[8][4];
    #pragma unroll
    for (int m = 0; m < 8; ++m)
        #pragma unroll
        for (int n = 0; n < 4; ++n)
            acc[m][n] = (f32x4){0.f, 0.f, 0.f, 0.f};

    char* buf0 = lds;                 // K-tile t   (compute)
    char* buf1 = lds + BUFBYTES;      // K-tile t+1 (in flight)
    char* buf2 = lds + 2 * BUFBYTES;  // K-tile t+2 (staging target)

    // ---- prologue: stage tiles 0 and 1, gate tile 0 ----
    gload_lds16(As0,      buf0 + ld0);
    gload_lds16(As1,      buf0 + ld1);
    gload_lds16(Bs0,      buf0 + ABYTES + ld0);
    gload_lds16(Bs1,      buf0 + ABYTES + ld1);
    gload_lds16(As0 + BK, buf1 + ld0);
    gload_lds16(As1 + BK, buf1 + ld1);
    gload_lds16(Bs0 + BK, buf1 + ABYTES + ld0);
    gload_lds16(Bs1 + BK, buf1 + ABYTES + ld1);
    asm volatile("s_waitcnt vmcnt(4)" ::: "memory");  // tile 0 landed (all waves after barrier)
    __builtin_amdgcn_s_barrier();

    #pragma unroll 1
    for (int kt = 0; kt < NKT; ++kt) {
        int kg = kt + 2; if (kg >= NKT) kg -= NKT;    // wrap: dead reload, write-safe
        const size_t go = (size_t)kg * BK;

        s16x8 af[8], bf[2];

        // ======== phase 1: n-half 0 ========
        #pragma unroll
        for (int m = 0; m < 8; ++m)
            af[m] = *(const s16x8*)(buf0 + aoff + m * 1024);
        #pragma unroll
        for (int n = 0; n < 2; ++n)
            bf[n] = *(const s16x8*)(buf0 + ABYTES + boff + n * 1024);
        gload_lds16(As0 + go, buf2 + ld0);            // stage A of tile kt+2
        gload_lds16(As1 + go, buf2 + ld1);
        __builtin_amdgcn_s_barrier();
        asm volatile("s_waitcnt lgkmcnt(0)" ::: "memory");
        __builtin_amdgcn_s_setprio(1);
        #pragma unroll
        for (int m = 0; m < 8; ++m) {
            acc[m][0] = MFMA(af[m], bf[0], acc[m][0]);
            acc[m][1] = MFMA(af[m], bf[1], acc[m][1]);
        }
        __builtin_amdgcn_s_setprio(0);
        __builtin_amdgcn_s_barrier();

        // ======== phase 2: n-half 1 ========
        #pragma unroll
        for (int n = 0; n < 2; ++n)
            bf[n] = *(const s16x8*)(buf0 + ABYTES + boff + 2048 + n * 1024);
        gload_lds16(Bs0 + go, buf2 + ABYTES + ld0);   // stage B of tile kt+2
        gload_lds16(Bs1 + go, buf2 + ABYTES + ld1);
        asm volatile("s_waitcnt vmcnt(4)" ::: "memory");  // tile kt+1 landed; kt+2 in flight
        __builtin_amdgcn_s_barrier();
        asm volatile("s_waitcnt lgkmcnt(0)" ::: "memory");
        __builtin_amdgcn_s_setprio(1);
        #pragma unroll
        for (int m = 0; m < 8; ++m) {
            acc[m][2] = MFMA(af[m], bf[0], acc[m][2]);
            acc[m][3] = MFMA(af[m], bf[1], acc[m][3]);
        }
        __builtin_amdgcn_s_setprio(0);
        __builtin_amdgcn_s_barrier();

        // rotate buffers
        char* t = buf0; buf0 = buf1; buf1 = buf2; buf2 = t;
    }

    asm volatile("s_waitcnt vmcnt(0)" ::: "memory");  // drain dangling prefetches

    // ---- epilogue: C/D layout col = lane&15, row = (lane>>4)*4 + j ----
    const int ccol0 = bcol + wn * 64 + fr;
    const int crow0 = brow + wm * 128 + l16 * 4;
    float bv[4];
    #pragma unroll
    for (int n = 0; n < 4; ++n) bv[n] = bias[ccol0 + n * 16];

    #pragma unroll
    for (int m = 0; m < 8; ++m) {
        #pragma unroll
        for (int j = 0; j < 4; ++j) {
            float* Crow = C + (size_t)(crow0 + m * 16 + j) * NDIM;
            #pragma unroll
            for (int n = 0; n < 4; ++n)
                Crow[ccol0 + n * 16] = acc[m][n][j] + bv[n];
        }
    }
}

// ---------------- launcher ----------------

extern "C" void kernel_launch(void* const* d_in, const int* in_sizes, int n_in,
                              void* d_out, int out_size, void* d_ws, size_t ws_size,
                              hipStream_t stream) {
    const float* x        = (const float*)d_in[0];  // [4,4096,2048]
    const float* weights  = (const float*)d_in[1];  // [16]
    const float* W        = (const float*)d_in[2];  // [2048,2048]
    const float* b        = (const float*)d_in[3];  // [2048]
    const float* a_scales = (const float*)d_in[4];  // [2]
    const float* w_scales = (const float*)d_in[5];  // [2]
    float* out = (float*)d_out;

    __hip_bfloat16* xq = (__hip_bfloat16*)d_ws;                            // 67108864 B
    __hip_bfloat16* wq = (__hip_bfloat16*)((char*)d_ws + 67108864);        //  8388608 B
    float*          bm = (float*)((char*)d_ws + 67108864 + 8388608);       //     8192 B

    prep_w<<<dim3((NDIM * KDIM) / (256 * 8)), dim3(256), 0, stream>>>(W, weights, w_scales, wq);
    prep_b<<<dim3(NDIM / 256), dim3(256), 0, stream>>>(b, weights, bm);
    prep_x<<<dim3(((size_t)MDIM * KDIM) / (256 * 8)), dim3(256), 0, stream>>>(x, weights, a_scales, xq);
    gemm256<<<dim3(NDIM / BN, MDIM / BM), dim3(512), 0, stream>>>(xq, wq, bm, out);
}

// Round 3
// 161.960 us; speedup vs baseline: 1.2611x; 1.1314x over previous
//
#include <hip/hip_runtime.h>
#include <hip/hip_bf16.h>
#include <stdint.h>

#define MDIM 16384   // B*S = 4*4096
#define NDIM 2048    // MAX_OUT
#define KDIM 2048    // MAX_IN

typedef __attribute__((ext_vector_type(4))) float f32x4;
typedef __attribute__((ext_vector_type(8))) short s16x8;

__device__ __forceinline__ void gload_lds16(const __hip_bfloat16* g, void* l) {
    __builtin_amdgcn_global_load_lds(
        (const __attribute__((address_space(1))) void*)g,
        (__attribute__((address_space(3))) void*)l,
        16, 0, 0);
}

// ---------------- prep kernels (unchanged, near-BW) ----------------

__global__ __launch_bounds__(256) void prep_x(
    const float* __restrict__ x, const float* __restrict__ weights,
    const float* __restrict__ a_scales, __hip_bfloat16* __restrict__ xq)
{
    float A0 = 0.f, A1 = 0.f;
    #pragma unroll
    for (int k = 0; k < 16; ++k) {
        float w = weights[k];
        if (((k >> 1) & 1) == 0) A0 += w; else A1 += w;
    }
    const float s0 = a_scales[0], s1 = a_scales[1];
    const float r0 = 1.f / s0, r1 = 1.f / s1;

    size_t idx = ((size_t)blockIdx.x * 256 + threadIdx.x) * 8;
    const f32x4* xv = (const f32x4*)(x + idx);
    f32x4 v0 = xv[0], v1 = xv[1];
    float vals[8] = {v0.x, v0.y, v0.z, v0.w, v1.x, v1.y, v1.z, v1.w};

    union { s16x8 v; __hip_bfloat16 h[8]; } u;
    #pragma unroll
    for (int j = 0; j < 8; ++j) {
        float q0 = rintf(fminf(fmaxf(vals[j] * r0, -8.f),   7.f)) * s0;
        float q1 = rintf(fminf(fmaxf(vals[j] * r1, -128.f), 127.f)) * s1;
        u.h[j] = __float2bfloat16(A0 * q0 + A1 * q1);
    }
    *(s16x8*)(xq + idx) = u.v;
}

__global__ __launch_bounds__(256) void prep_w(
    const float* __restrict__ W, const float* __restrict__ weights,
    const float* __restrict__ w_scales, __hip_bfloat16* __restrict__ wq)
{
    float c00 = weights[0] + weights[2]  + weights[4]  + weights[6];
    float c01 = weights[1] + weights[3]  + weights[5]  + weights[7];
    float c10 = weights[8] + weights[10] + weights[12] + weights[14];
    float c11 = weights[9] + weights[11] + weights[13] + weights[15];

    const float s0 = w_scales[0], s1 = w_scales[1];
    const float r0 = 1.f / s0, r1 = 1.f / s1;

    size_t idx = ((size_t)blockIdx.x * 256 + threadIdx.x) * 8;
    const int o = (int)(idx >> 11);
    const int c = (int)(idx & 2047);
    const bool inner = (o < 1024) && (c < 1024);
    const float k0 = inner ? (c00 + c10) : c10;
    const float k1 = inner ? (c01 + c11) : c11;

    const f32x4* wv = (const f32x4*)(W + idx);
    f32x4 v0 = wv[0], v1 = wv[1];
    float vals[8] = {v0.x, v0.y, v0.z, v0.w, v1.x, v1.y, v1.z, v1.w};

    union { s16x8 v; __hip_bfloat16 h[8]; } u;
    #pragma unroll
    for (int j = 0; j < 8; ++j) {
        float q0 = rintf(fminf(fmaxf(vals[j] * r0, -8.f),   7.f)) * s0;
        float q1 = rintf(fminf(fmaxf(vals[j] * r1, -128.f), 127.f)) * s1;
        u.h[j] = __float2bfloat16(k0 * q0 + k1 * q1);
    }
    *(s16x8*)(wq + idx) = u.v;
}

__global__ __launch_bounds__(256) void prep_b(
    const float* __restrict__ b, const float* __restrict__ weights,
    float* __restrict__ bm)
{
    int o = blockIdx.x * 256 + threadIdx.x;
    if (o >= NDIM) return;
    float S1 = 0.f, S0 = 0.f;
    #pragma unroll
    for (int k = 0; k < 8; ++k)  S0 += weights[k];
    #pragma unroll
    for (int k = 8; k < 16; ++k) S1 += weights[k];
    bm[o] = b[o] * ((o < 1024) ? (S0 + S1) : S1);
}

// ---------------- GEMM: 256x256 tile, BK=32, 8 waves, triple-buffered LDS,
// register-subtile pipelined one phase ahead, counted lgkm/vmcnt, T1+T2+T5 ----

#define BM 256
#define BN 256
#define BK 32
#define NKT (KDIM / BK)          // 64
#define ABYTES (BM * BK * 2)     // 16384 bytes per A-tile
#define BUFBYTES (2 * ABYTES)    // 32768 bytes per K-tile buffer (A+B)

#define MFMA(a, b, c) __builtin_amdgcn_mfma_f32_16x16x32_bf16((a), (b), (c), 0, 0, 0)

// One K-tile, register-pipelined. AFU/BF0U: fragments of tile t (ready).
// AFL/BF0L: loaded here with tile t+1's fragments for next call.
#define KTILE(AFU, AFL, BF0U, BF0L)                                          \
  {                                                                          \
    const char* curB_ = cur + ABYTES;                                        \
    const char* nxtB_ = nxt + ABYTES;                                        \
    const size_t go_ = (size_t)kg * BK;                                      \
    /* S1: bf1 of current tile */                                            \
    bf1[0] = *(const s16x8*)(curB_ + boff + 2048);                           \
    bf1[1] = *(const s16x8*)(curB_ + boff + 3072);                           \
    /* S2: stage A(t+2) */                                                   \
    gload_lds16(As0 + go_, stg + ld0);                                       \
    gload_lds16(As1 + go_, stg + ld1);                                       \
    /* S3: af/bf0 (issued last tile) complete; bf1 may still fly */          \
    asm volatile("s_waitcnt lgkmcnt(2)" ::: "memory");                       \
    __builtin_amdgcn_sched_barrier(0);                                       \
    /* S4: MFMA cluster 0 (n-half 0) */                                      \
    __builtin_amdgcn_s_setprio(1);                                           \
    _Pragma("unroll")                                                        \
    for (int m_ = 0; m_ < 8; ++m_) {                                         \
      acc[m_][0] = MFMA(AFU[m_], BF0U[0], acc[m_][0]);                       \
      acc[m_][1] = MFMA(AFU[m_], BF0U[1], acc[m_][1]);                       \
    }                                                                        \
    __builtin_amdgcn_s_setprio(0);                                           \
    /* S5: tile t+1 fully landed (only A(t+2)'s 2 loads may remain) */       \
    asm volatile("s_waitcnt vmcnt(2)" ::: "memory");                         \
    /* S6: all waves' t+1 staging landed before any frag read of it */       \
    __builtin_amdgcn_s_barrier();                                            \
    /* S7: prefetch tile t+1's af/bf0 (consumed next call) */                \
    _Pragma("unroll")                                                        \
    for (int m_ = 0; m_ < 8; ++m_)                                           \
      AFL[m_] = *(const s16x8*)(nxt + aoff + m_ * 1024);                     \
    BF0L[0] = *(const s16x8*)(nxtB_ + boff);                                 \
    BF0L[1] = *(const s16x8*)(nxtB_ + boff + 1024);                          \
    /* S8: stage B(t+2) */                                                   \
    gload_lds16(Bs0 + go_, stg + ABYTES + ld0);                              \
    gload_lds16(Bs1 + go_, stg + ABYTES + ld1);                              \
    /* S9: bf1 complete; the 10 prefetch reads still fly under M1 */         \
    asm volatile("s_waitcnt lgkmcnt(10)" ::: "memory");                      \
    __builtin_amdgcn_sched_barrier(0);                                       \
    /* S10: MFMA cluster 1 (n-half 1) */                                     \
    __builtin_amdgcn_s_setprio(1);                                           \
    _Pragma("unroll")                                                        \
    for (int m_ = 0; m_ < 8; ++m_) {                                         \
      acc[m_][2] = MFMA(AFU[m_], bf1[0], acc[m_][2]);                        \
      acc[m_][3] = MFMA(AFU[m_], bf1[1], acc[m_][3]);                        \
    }                                                                        \
    __builtin_amdgcn_s_setprio(0);                                           \
    /* S11: closes tile t; buffer(t) reads all retired (S3/S9) -> next-iter  \
       staging into it is write-after-read safe */                           \
    __builtin_amdgcn_s_barrier();                                            \
    { char* t_ = cur; cur = nxt; nxt = stg; stg = t_; }                      \
    kg = (kg + 1) & (NKT - 1);                                               \
  }

__global__ __launch_bounds__(512, 2) void gemm256(
    const __hip_bfloat16* __restrict__ A,
    const __hip_bfloat16* __restrict__ B,
    const float* __restrict__ bias,
    float* __restrict__ C)
{
    __shared__ char lds[3 * BUFBYTES];   // 96 KiB

    const int tid  = threadIdx.x;
    const int lane = tid & 63;
    const int wid  = tid >> 6;    // 0..7
    const int wm   = wid >> 2;    // 0..1  (M half)
    const int wn   = wid & 3;     // 0..3  (N quarter)

    // T1: bijective XCD-chunked swizzle (512 blocks, 8 XCDs, 64 blocks each).
    // Blocks sharing an A row-panel (8 consecutive bx) land on ONE XCD's L2.
    const int bid  = blockIdx.y * gridDim.x + blockIdx.x;  // x fastest
    const int swz  = (bid & 7) * 64 + (bid >> 3);
    const int brow = (swz >> 3) * BM;
    const int bcol = (swz & 7) * BN;

    // ---- staging: linear LDS dest, pre-swizzled global source (T2) ----
    const int i0 = tid, i1 = tid + 512;
    const int r0 = i0 >> 2, c0 = (i0 & 3) ^ ((i0 >> 3) & 3);
    const int r1 = i1 >> 2, c1 = (i1 & 3) ^ ((i1 >> 3) & 3);
    const __hip_bfloat16* As0 = A + (size_t)(brow + r0) * KDIM + c0 * 8;
    const __hip_bfloat16* As1 = A + (size_t)(brow + r1) * KDIM + c1 * 8;
    const __hip_bfloat16* Bs0 = B + (size_t)(bcol + r0) * KDIM + c0 * 8;
    const __hip_bfloat16* Bs1 = B + (size_t)(bcol + r1) * KDIM + c1 * 8;
    const int ld0 = i0 * 16, ld1 = i1 * 16;

    // ---- fragment-read constants (swizzled; XOR lane-constant) ----
    const int fr  = lane & 15;
    const int l16 = lane >> 4;
    const int xr  = (l16 ^ ((fr >> 1) & 3)) * 16;
    const int aoff = (wm * 128 + fr) * 64 + xr;
    const int boff = (wn * 64  + fr) * 64 + xr;

    f32x4 acc[8][4];
    #pragma unroll
    for (int m = 0; m < 8; ++m)
        #pragma unroll
        for (int n = 0; n < 4; ++n)
            acc[m][n] = (f32x4){0.f, 0.f, 0.f, 0.f};

    s16x8 afA[8], afB[8], bf0A[2], bf0B[2], bf1[2];

    char* cur = lds;
    char* nxt = lds + BUFBYTES;
    char* stg = lds + 2 * BUFBYTES;
    int kg = 2;   // global K-tile index to stage next

    // ---- prologue: stage tiles 0,1; gate tile 0; prefetch its fragments ----
    gload_lds16(As0,      cur + ld0);
    gload_lds16(As1,      cur + ld1);
    gload_lds16(Bs0,      cur + ABYTES + ld0);
    gload_lds16(Bs1,      cur + ABYTES + ld1);
    gload_lds16(As0 + BK, nxt + ld0);
    gload_lds16(As1 + BK, nxt + ld1);
    gload_lds16(Bs0 + BK, nxt + ABYTES + ld0);
    gload_lds16(Bs1 + BK, nxt + ABYTES + ld1);
    asm volatile("s_waitcnt vmcnt(4)" ::: "memory");   // tile 0 landed
    __builtin_amdgcn_s_barrier();
    #pragma unroll
    for (int m = 0; m < 8; ++m)
        afA[m] = *(const s16x8*)(cur + aoff + m * 1024);
    bf0A[0] = *(const s16x8*)(cur + ABYTES + boff);
    bf0A[1] = *(const s16x8*)(cur + ABYTES + boff + 1024);

    #pragma unroll 1
    for (int kt = 0; kt < NKT; kt += 2) {
        KTILE(afA, afB, bf0A, bf0B);   // tile kt
        KTILE(afB, afA, bf0B, bf0A);   // tile kt+1
    }
    asm volatile("s_waitcnt vmcnt(0)" ::: "memory");   // drain wrap prefetches

    // ---- epilogue: C/D layout col = lane&15, row = (lane>>4)*4 + j ----
    const int ccol0 = bcol + wn * 64 + fr;
    const int crow0 = brow + wm * 128 + l16 * 4;
    float bv[4];
    #pragma unroll
    for (int n = 0; n < 4; ++n) bv[n] = bias[ccol0 + n * 16];

    #pragma unroll
    for (int m = 0; m < 8; ++m) {
        #pragma unroll
        for (int j = 0; j < 4; ++j) {
            float* Crow = C + (size_t)(crow0 + m * 16 + j) * NDIM;
            #pragma unroll
            for (int n = 0; n < 4; ++n)
                Crow[ccol0 + n * 16] = acc[m][n][j] + bv[n];
        }
    }
}

// ---------------- launcher ----------------

extern "C" void kernel_launch(void* const* d_in, const int* in_sizes, int n_in,
                              void* d_out, int out_size, void* d_ws, size_t ws_size,
                              hipStream_t stream) {
    const float* x        = (const float*)d_in[0];  // [4,4096,2048]
    const float* weights  = (const float*)d_in[1];  // [16]
    const float* W        = (const float*)d_in[2];  // [2048,2048]
    const float* b        = (const float*)d_in[3];  // [2048]
    const float* a_scales = (const float*)d_in[4];  // [2]
    const float* w_scales = (const float*)d_in[5];  // [2]
    float* out = (float*)d_out;

    __hip_bfloat16* xq = (__hip_bfloat16*)d_ws;                            // 67108864 B
    __hip_bfloat16* wq = (__hip_bfloat16*)((char*)d_ws + 67108864);        //  8388608 B
    float*          bm = (float*)((char*)d_ws + 67108864 + 8388608);       //     8192 B

    prep_w<<<dim3((NDIM * KDIM) / (256 * 8)), dim3(256), 0, stream>>>(W, weights, w_scales, wq);
    prep_b<<<dim3(NDIM / 256), dim3(256), 0, stream>>>(b, weights, bm);
    prep_x<<<dim3(((size_t)MDIM * KDIM) / (256 * 8)), dim3(256), 0, stream>>>(x, weights, a_scales, xq);
    gemm256<<<dim3(NDIM / BN, MDIM / BM), dim3(512), 0, stream>>>(xq, wq, bm, out);
}